// Round 2
// baseline (201.931 us; speedup 1.0000x reference)
//
#include <hip/hip_runtime.h>

#define NODE 100
#define BATCH 64
#define DIM 128
#define IN_DIM 5
#define TOPK 30
#define INTER 256
#define NB (BATCH*NODE)   /* 6400 */
#define EPS 1e-5f
#define SLOPE 0.2f

// ---------------- K1: h = x @ w_lin^T ; per-row attention scalars ai, aj ----
__global__ __launch_bounds__(128) void k_lin_att(
        const float* __restrict__ x, const float* __restrict__ emb,
        const float* __restrict__ w_lin,
        const float* __restrict__ att_i, const float* __restrict__ att_j,
        const float* __restrict__ att_em_i, const float* __restrict__ att_em_j,
        float* __restrict__ h, float* __restrict__ ai, float* __restrict__ aj) {
    int row = blockIdx.x;
    int d = threadIdx.x;              // 0..127
    int node = row % NODE;
    float xv[IN_DIM];
#pragma unroll
    for (int c = 0; c < IN_DIM; ++c) xv[c] = x[row*IN_DIM + c];
    float hv = 0.f;
#pragma unroll
    for (int c = 0; c < IN_DIM; ++c) hv += xv[c] * w_lin[d*IN_DIM + c];
    h[row*DIM + d] = hv;
    float e = emb[node*DIM + d];
    float si = hv*att_i[d] + e*att_em_i[d];
    float sj = hv*att_j[d] + e*att_em_j[d];
    __shared__ float s1[DIM], s2[DIM];
    s1[d] = si; s2[d] = sj;
    __syncthreads();
    for (int off = 64; off > 0; off >>= 1) {
        if (d < off) { s1[d] += s1[d+off]; s2[d] += s2[d+off]; }
        __syncthreads();
    }
    if (d == 0) { ai[row] = s1[0]; aj[row] = s2[0]; }
}

// ---------------- K2: cosine similarity rows + iterative top-30 -------------
__global__ __launch_bounds__(128) void k_topk(const float* __restrict__ emb,
                                              int* __restrict__ idx) {
    int i = blockIdx.x;   // 0..99
    int t = threadIdx.x;  // 0..127
    __shared__ float ei[DIM];
    __shared__ float cosv[NODE];
    __shared__ float rv[128];
    __shared__ int   ri[128];
    ei[t] = emb[i*DIM + t];
    __syncthreads();
    float ni = 0.f;
#pragma unroll
    for (int dd = 0; dd < DIM; ++dd) ni += ei[dd]*ei[dd];
    if (t < NODE) {
        float s = 0.f, nj = 0.f;
        for (int dd = 0; dd < DIM; ++dd) {
            float e = emb[t*DIM + dd];
            s += ei[dd]*e;
            nj += e*e;
        }
        cosv[t] = s / (sqrtf(ni) * sqrtf(nj));
    }
    __syncthreads();
    for (int r = 0; r < TOPK; ++r) {
        float v = (t < NODE) ? cosv[t] : -INFINITY;
        rv[t] = v; ri[t] = t;
        __syncthreads();
        for (int off = 64; off > 0; off >>= 1) {
            if (t < off) {
                float v2 = rv[t+off]; int i2 = ri[t+off];
                if (v2 > rv[t] || (v2 == rv[t] && i2 < ri[t])) { rv[t] = v2; ri[t] = i2; }
            }
            __syncthreads();
        }
        if (t == 0) {
            idx[i*TOPK + r] = ri[0];
            cosv[ri[0]] = -INFINITY;   // exclude; tie-break = lowest index, matches lax.top_k
        }
        __syncthreads();
    }
}

// ------- K3: per-target edge attention + 30-way softmax + weighted gather ---
__global__ __launch_bounds__(128) void k_attagg(
        const float* __restrict__ h, const float* __restrict__ ai,
        const float* __restrict__ aj, const int* __restrict__ idx,
        const float* __restrict__ g_bias, float* __restrict__ agg) {
    int tgt = blockIdx.x;       // 0..6399
    int t = threadIdx.x;        // 0..127
    int node = tgt % NODE;
    int base = (tgt / NODE) * NODE;
    __shared__ float w[TOPK];
    __shared__ int   srcs[TOPK];
    if (t < TOPK) {
        int s = base + idx[node*TOPK + t];
        srcs[t] = s;
        float a = ai[tgt] + aj[s];
        a = (a > 0.f) ? a : SLOPE*a;   // leaky relu
        w[t] = a;
    }
    __syncthreads();
    if (t == 0) {
        float m = -INFINITY;
        for (int r = 0; r < TOPK; ++r) m = fmaxf(m, w[r]);
        float s = 0.f;
        for (int r = 0; r < TOPK; ++r) { float e = expf(w[r]-m); w[r] = e; s += e; }
        float inv = 1.f/(s + 1e-16f);
        for (int r = 0; r < TOPK; ++r) w[r] *= inv;
    }
    __syncthreads();
    float acc = 0.f;
#pragma unroll 5
    for (int r = 0; r < TOPK; ++r) {
        acc += w[r] * h[srcs[r]*DIM + t];
    }
    agg[tgt*DIM + t] = acc + g_bias[t];
}

// ---------------- per-channel BatchNorm stats (mean, rstd) ------------------
__global__ __launch_bounds__(256) void k_stats(const float* __restrict__ src, int C,
                                               float* __restrict__ mu,
                                               float* __restrict__ rs) {
    int c = blockIdx.x;
    int t = threadIdx.x;  // 256
    float s = 0.f, s2 = 0.f;
    for (int r = t; r < NB; r += 256) {
        float v = src[r*C + c];
        s += v; s2 += v*v;
    }
    __shared__ float a1[256], a2[256];
    a1[t] = s; a2[t] = s2;
    __syncthreads();
    for (int off = 128; off > 0; off >>= 1) {
        if (t < off) { a1[t] += a1[t+off]; a2[t] += a2[t+off]; }
        __syncthreads();
    }
    if (t == 0) {
        float m = a1[0] / (float)NB;
        float var = a2[0]/(float)NB - m*m;
        mu[c] = m;
        rs[c] = rsqrtf(var + EPS);
    }
}

// ---------------- K5: x3 = relu(bn1(agg)) * emb ----------------------------
__global__ __launch_bounds__(256) void k_x3(
        const float* __restrict__ agg, const float* __restrict__ emb,
        const float* __restrict__ mu1, const float* __restrict__ rs1,
        const float* __restrict__ g1, const float* __restrict__ b1,
        float* __restrict__ x3) {
    int i = blockIdx.x*256 + threadIdx.x;
    if (i >= NB*DIM) return;
    int d = i & (DIM-1);
    int row = i >> 7;
    int node = row % NODE;
    float v = (agg[i] - mu1[d]) * rs1[d] * g1[d] + b1[d];
    v = fmaxf(v, 0.f);
    x3[i] = v * emb[node*DIM + d];
}

// ------- K7: o1 = relu(bn2(x3)) @ w1^T + b1  (6400x128 @ 128x256) ----------
__global__ __launch_bounds__(256) void k_gemm1(
        const float* __restrict__ x3,
        const float* __restrict__ mu2, const float* __restrict__ rs2,
        const float* __restrict__ g2, const float* __restrict__ b2v,
        const float* __restrict__ w1, const float* __restrict__ b1v,
        float* __restrict__ o1) {
    __shared__ float aT[32][36];       // 32 rows x 32 k (pad 36: float4-aligned, conflict-free)
    __shared__ float wT[32][260];      // 32 k x 256 cols (pad 260)
    int tid = threadIdx.x;
    int r0 = blockIdx.x * 32;
    int cg = tid & 63;      // cols cg*4..+3
    int rg = tid >> 6;      // rows rg*8..+7
    float acc[8][4];
#pragma unroll
    for (int a = 0; a < 8; ++a)
#pragma unroll
        for (int b = 0; b < 4; ++b) acc[a][b] = 0.f;

    for (int k0 = 0; k0 < DIM; k0 += 32) {
        // A tile with bn2 + relu fused
#pragma unroll
        for (int j = 0; j < 4; ++j) {
            int i = tid + j*256;
            int kk = i & 31, row = i >> 5;
            int k = k0 + kk;
            float v = (x3[(r0+row)*DIM + k] - mu2[k]) * rs2[k] * g2[k] + b2v[k];
            aT[row][kk] = fmaxf(v, 0.f);
        }
        // W tile: wT[kk][c] = w1[c][k0+kk]
#pragma unroll
        for (int j = 0; j < 32; ++j) {
            int i = tid + j*256;
            int kk = i & 31, c = i >> 5;
            wT[kk][c] = w1[c*DIM + k0 + kk];
        }
        __syncthreads();
#pragma unroll
        for (int q4 = 0; q4 < 8; ++q4) {
            float4 av[8], wv[4];
#pragma unroll
            for (int rr = 0; rr < 8; ++rr)
                av[rr] = *(const float4*)&aT[rg*8+rr][q4*4];
#pragma unroll
            for (int q = 0; q < 4; ++q)
                wv[q] = *(const float4*)&wT[q4*4+q][cg*4];
#pragma unroll
            for (int rr = 0; rr < 8; ++rr) {
                acc[rr][0] += av[rr].x*wv[0].x + av[rr].y*wv[1].x + av[rr].z*wv[2].x + av[rr].w*wv[3].x;
                acc[rr][1] += av[rr].x*wv[0].y + av[rr].y*wv[1].y + av[rr].z*wv[2].y + av[rr].w*wv[3].y;
                acc[rr][2] += av[rr].x*wv[0].z + av[rr].y*wv[1].z + av[rr].z*wv[2].z + av[rr].w*wv[3].z;
                acc[rr][3] += av[rr].x*wv[0].w + av[rr].y*wv[1].w + av[rr].z*wv[2].w + av[rr].w*wv[3].w;
            }
        }
        __syncthreads();
    }
    int cbase = cg*4;
    float4 bv = *(const float4*)&b1v[cbase];
#pragma unroll
    for (int rr = 0; rr < 8; ++rr) {
        int row = r0 + rg*8 + rr;
        float4 o;
        o.x = acc[rr][0] + bv.x;
        o.y = acc[rr][1] + bv.y;
        o.z = acc[rr][2] + bv.z;
        o.w = acc[rr][3] + bv.w;
        *(float4*)&o1[row*INTER + cbase] = o;
    }
}

// ---------------- K9: out = relu(bn3(o1)) @ w2^T + b2 ----------------------
__global__ __launch_bounds__(256) void k_out(
        const float* __restrict__ o1,
        const float* __restrict__ mu3, const float* __restrict__ rs3,
        const float* __restrict__ g3, const float* __restrict__ b3,
        const float* __restrict__ w2, const float* __restrict__ b2s,
        float* __restrict__ out) {
    int row = blockIdx.x;
    int c = threadIdx.x; // 256
    float v = (o1[row*INTER + c] - mu3[c]) * rs3[c] * g3[c] + b3[c];
    v = fmaxf(v, 0.f);
    v *= w2[c];
    __shared__ float red[256];
    red[c] = v;
    __syncthreads();
    for (int off = 128; off > 0; off >>= 1) {
        if (c < off) red[c] += red[c+off];
        __syncthreads();
    }
    if (c == 0) out[row] = red[0] + b2s[0];
}

extern "C" void kernel_launch(void* const* d_in, const int* in_sizes, int n_in,
                              void* d_out, int out_size, void* d_ws, size_t ws_size,
                              hipStream_t stream) {
    const float* x        = (const float*)d_in[0];
    const float* emb      = (const float*)d_in[1];
    const float* w_lin    = (const float*)d_in[2];
    const float* att_i    = (const float*)d_in[3];
    const float* att_j    = (const float*)d_in[4];
    const float* att_em_i = (const float*)d_in[5];
    const float* att_em_j = (const float*)d_in[6];
    const float* g_bias   = (const float*)d_in[7];
    const float* bn1_g    = (const float*)d_in[8];
    const float* bn1_b    = (const float*)d_in[9];
    const float* bn2_g    = (const float*)d_in[10];
    const float* bn2_b    = (const float*)d_in[11];
    const float* bn3_g    = (const float*)d_in[12];
    const float* bn3_b    = (const float*)d_in[13];
    const float* w1       = (const float*)d_in[14];
    const float* b1       = (const float*)d_in[15];
    const float* w2       = (const float*)d_in[16];
    const float* b2       = (const float*)d_in[17];
    float* out = (float*)d_out;

    float* ws  = (float*)d_ws;
    float* h   = ws;                 // 6400*128
    float* agg = ws + 819200;        // 6400*128
    float* x3  = ws + 1638400;       // 6400*128
    float* o1  = ws + 2457600;       // 6400*256
    float* ai  = ws + 4096000;       // 6400
    float* aj  = ws + 4102400;       // 6400
    float* mu1 = ws + 4108800;
    float* rs1 = mu1 + 128;
    float* mu2 = rs1 + 128;
    float* rs2 = mu2 + 128;
    float* mu3 = rs2 + 128;
    float* rs3 = mu3 + 256;
    int*   idx = (int*)(ws + 4110000); // 100*30 ints

    k_lin_att<<<NB, 128, 0, stream>>>(x, emb, w_lin, att_i, att_j, att_em_i,
                                      att_em_j, h, ai, aj);
    k_topk<<<NODE, 128, 0, stream>>>(emb, idx);
    k_attagg<<<NB, 128, 0, stream>>>(h, ai, aj, idx, g_bias, agg);
    k_stats<<<DIM, 256, 0, stream>>>(agg, DIM, mu1, rs1);
    k_x3<<<(NB*DIM + 255)/256, 256, 0, stream>>>(agg, emb, mu1, rs1, bn1_g, bn1_b, x3);
    k_stats<<<DIM, 256, 0, stream>>>(x3, DIM, mu2, rs2);
    k_gemm1<<<NB/32, 256, 0, stream>>>(x3, mu2, rs2, bn2_g, bn2_b, w1, b1, o1);
    k_stats<<<INTER, 256, 0, stream>>>(o1, INTER, mu3, rs3);
    k_out<<<NB, 256, 0, stream>>>(o1, mu3, rs3, bn3_g, bn3_b, w2, b2, out);
}